// Round 1
// baseline (98.484 us; speedup 1.0000x reference)
//
#include <hip/hip_runtime.h>
#include <hip/hip_bf16.h>

// RBF: out[b][o] = exp(-max(||x_b||^2 - 2 x_b.c_o + ||c_o||^2, 0) * exp(-2*log_sigma_o))
// B=8192, IN=512, OUT=1024, fp32 in/out. Cross term via bf16 MFMA (no fp32 MFMA on CDNA4).

#define B_ROWS 8192
#define IN_K   512
#define OUT_N  1024

#define BM 128
#define BN 128
#define BK 32          // K elements per LDS tile
#define LDT 40         // padded LDS row length (bf16 elems): 80B rows -> 2-way-ish bank pattern

typedef __attribute__((ext_vector_type(8))) __bf16 bf16x8;
typedef __attribute__((ext_vector_type(4))) __bf16 bf16x4;
typedef __attribute__((ext_vector_type(4))) float  floatx4;

// ---------------- row sum-of-squares (cols fixed at 512) ----------------
__global__ void rowsumsq_512(const float* __restrict__ x, float* __restrict__ out, int rows) {
    int gt   = blockIdx.x * blockDim.x + threadIdx.x;
    int wave = gt >> 6;
    int lane = threadIdx.x & 63;
    if (wave >= rows) return;
    const float4* r4 = reinterpret_cast<const float4*>(x + (size_t)wave * IN_K);
    float4 a = r4[lane];
    float4 b = r4[lane + 64];
    float s = a.x*a.x + a.y*a.y + a.z*a.z + a.w*a.w
            + b.x*b.x + b.y*b.y + b.z*b.z + b.w*b.w;
    #pragma unroll
    for (int off = 32; off; off >>= 1) s += __shfl_xor(s, off, 64);
    if (lane == 0) out[wave] = s;
}

// ---------------- fused GEMM + RBF epilogue ----------------
__global__ __launch_bounds__(256, 2) void rbf_gemm(
    const float* __restrict__ X,    // [8192][512]
    const float* __restrict__ C,    // [1024][512]
    const float* __restrict__ LS,   // [1024] log_sigmas
    const float* __restrict__ xsq,  // [8192]
    const float* __restrict__ csq,  // [1024]
    float* __restrict__ out)        // [8192][1024]
{
    __shared__ __bf16 As[BM * LDT];
    __shared__ __bf16 Bs[BN * LDT];

    const int tid  = threadIdx.x;
    const int bn   = blockIdx.x & 7;    // OUT_N / BN = 8
    const int bm   = blockIdx.x >> 3;   // B_ROWS / BM = 64
    const int brow = bm * BM;
    const int bcol = bn * BN;
    const int w    = tid >> 6;
    const int lane = tid & 63;
    const int wr   = w >> 1;            // 2x2 wave grid, each wave 64x64
    const int wc   = w & 1;
    const int l15  = lane & 15;
    const int l4   = lane >> 4;

    floatx4 acc[4][4];
    #pragma unroll
    for (int m = 0; m < 4; ++m)
        #pragma unroll
        for (int n = 0; n < 4; ++n)
            acc[m][n] = (floatx4){0.f, 0.f, 0.f, 0.f};

    // Staging: 128 rows x 32 k = 1024 float4s; 256 threads x 4 each.
    float4 ar[4], br[4];

    auto load_tile = [&](int kt, float4* a, float4* b) {
        #pragma unroll
        for (int i = 0; i < 4; ++i) {
            int lin = i * 256 + tid;
            int r   = lin >> 3;
            int c4  = lin & 7;
            a[i] = *reinterpret_cast<const float4*>(X + (size_t)(brow + r) * IN_K + kt * BK + c4 * 4);
            b[i] = *reinterpret_cast<const float4*>(C + (size_t)(bcol + r) * IN_K + kt * BK + c4 * 4);
        }
    };
    auto store_tile = [&](const float4* a, const float4* b) {
        #pragma unroll
        for (int i = 0; i < 4; ++i) {
            int lin = i * 256 + tid;
            int r   = lin >> 3;
            int c4  = lin & 7;
            bf16x4 va = { (__bf16)a[i].x, (__bf16)a[i].y, (__bf16)a[i].z, (__bf16)a[i].w };
            bf16x4 vb = { (__bf16)b[i].x, (__bf16)b[i].y, (__bf16)b[i].z, (__bf16)b[i].w };
            *reinterpret_cast<bf16x4*>(&As[r * LDT + c4 * 4]) = va;
            *reinterpret_cast<bf16x4*>(&Bs[r * LDT + c4 * 4]) = vb;
        }
    };

    load_tile(0, ar, br);

    const int NKT = IN_K / BK;  // 16
    #pragma unroll 1
    for (int kt = 0; kt < NKT; ++kt) {
        if (kt) __syncthreads();
        store_tile(ar, br);
        __syncthreads();

        float4 ar2[4], br2[4];
        if (kt < NKT - 1) load_tile(kt + 1, ar2, br2);

        bf16x8 af[4], bfr[4];
        #pragma unroll
        for (int m = 0; m < 4; ++m)
            af[m] = *reinterpret_cast<const bf16x8*>(&As[(wr * 64 + m * 16 + l15) * LDT + l4 * 8]);
        #pragma unroll
        for (int n = 0; n < 4; ++n)
            bfr[n] = *reinterpret_cast<const bf16x8*>(&Bs[(wc * 64 + n * 16 + l15) * LDT + l4 * 8]);

        #pragma unroll
        for (int m = 0; m < 4; ++m)
            #pragma unroll
            for (int n = 0; n < 4; ++n)
                acc[m][n] = __builtin_amdgcn_mfma_f32_16x16x32_bf16(af[m], bfr[n], acc[m][n], 0, 0, 0);

        #pragma unroll
        for (int i = 0; i < 4; ++i) { ar[i] = ar2[i]; br[i] = br2[i]; }
    }

    // Epilogue: d2 = max(xsq + csq - 2*cross, 0); out = exp(-d2 * exp(-2*ls))
    float xs[4][4];
    #pragma unroll
    for (int m = 0; m < 4; ++m) {
        int row0 = brow + wr * 64 + m * 16 + l4 * 4;
        #pragma unroll
        for (int r = 0; r < 4; ++r) xs[m][r] = xsq[row0 + r];
    }

    #pragma unroll
    for (int n = 0; n < 4; ++n) {
        int col   = bcol + wc * 64 + n * 16 + l15;
        float cs  = csq[col];
        float inv = __expf(-2.f * LS[col]);
        #pragma unroll
        for (int m = 0; m < 4; ++m) {
            int row0 = brow + wr * 64 + m * 16 + l4 * 4;
            #pragma unroll
            for (int r = 0; r < 4; ++r) {
                float cross = acc[m][n][r];
                float d2 = fmaxf(xs[m][r] + cs - 2.f * cross, 0.f);
                out[(size_t)(row0 + r) * OUT_N + col] = __expf(-d2 * inv);
            }
        }
    }
}

extern "C" void kernel_launch(void* const* d_in, const int* in_sizes, int n_in,
                              void* d_out, int out_size, void* d_ws, size_t ws_size,
                              hipStream_t stream) {
    const float* X  = (const float*)d_in[0];   // input   [8192][512]
    const float* C  = (const float*)d_in[1];   // centres [1024][512]
    const float* LS = (const float*)d_in[2];   // log_sigmas [1024]
    float* out = (float*)d_out;
    float* xsq = (float*)d_ws;                 // 8192 floats
    float* csq = xsq + B_ROWS;                 // 1024 floats

    rowsumsq_512<<<B_ROWS / 4, 256, 0, stream>>>(X, xsq, B_ROWS);
    rowsumsq_512<<<OUT_N / 4, 256, 0, stream>>>(C, csq, OUT_N);
    rbf_gemm<<<(B_ROWS / BM) * (OUT_N / BN), 256, 0, stream>>>(X, C, LS, xsq, csq, out);
}

// Round 2
// 88.140 us; speedup vs baseline: 1.1174x; 1.1174x over previous
//
#include <hip/hip_runtime.h>
#include <hip/hip_bf16.h>

// RBF: out[b][o] = exp(-max(||x_b||^2 - 2 x_b.c_o + ||c_o||^2, 0) * exp(-2*log_sigma_o))
// B=8192, IN=512, OUT=1024, fp32 in/out.
// Pass 1: fused fp32->bf16 convert + row sum-of-squares for X and C (into d_ws).
// Pass 2: bf16 MFMA GEMM (128x128 tile, BK=64, global_load_lds dwordx4, dbuf LDS,
//         1 barrier/K-step, slot-XOR swizzle via inverse-swizzled global source).

#define B_ROWS 8192
#define IN_K   512
#define OUT_N  1024
#define BK     64
#define NKT    (IN_K / BK)   // 8

typedef __attribute__((ext_vector_type(8))) __bf16 bf16x8;
typedef __attribute__((ext_vector_type(4))) __bf16 bf16x4;
typedef __attribute__((ext_vector_type(4))) float  floatx4;

__device__ __forceinline__ void gload_lds16(const void* g, void* l) {
    __builtin_amdgcn_global_load_lds((const __attribute__((address_space(1))) void*)g,
                                     (__attribute__((address_space(3))) void*)l,
                                     16, 0, 0);
}

// ---- pass 1: convert fp32 row -> bf16 row, emit sum of squares. 1 wave per row. ----
__global__ __launch_bounds__(256) void convert_sumsq(
    const float* __restrict__ X, const float* __restrict__ C,
    __bf16* __restrict__ Xbf, __bf16* __restrict__ Cbf,
    float* __restrict__ xsq, float* __restrict__ csq)
{
    int wid  = (blockIdx.x * 256 + threadIdx.x) >> 6;   // 0..9215
    int lane = threadIdx.x & 63;
    const float* src; __bf16* dst; float* sq;
    if (wid < B_ROWS) {
        src = X + (size_t)wid * IN_K; dst = Xbf + (size_t)wid * IN_K; sq = xsq + wid;
    } else {
        int r = wid - B_ROWS;
        src = C + (size_t)r * IN_K;  dst = Cbf + (size_t)r * IN_K;  sq = csq + r;
    }
    const float4* s4 = reinterpret_cast<const float4*>(src);
    float4 a = s4[lane];
    float4 b = s4[lane + 64];
    bf16x4 va = {(__bf16)a.x, (__bf16)a.y, (__bf16)a.z, (__bf16)a.w};
    bf16x4 vb = {(__bf16)b.x, (__bf16)b.y, (__bf16)b.z, (__bf16)b.w};
    *reinterpret_cast<bf16x4*>(dst + lane * 4)       = va;
    *reinterpret_cast<bf16x4*>(dst + 256 + lane * 4) = vb;
    float s = a.x*a.x + a.y*a.y + a.z*a.z + a.w*a.w
            + b.x*b.x + b.y*b.y + b.z*b.z + b.w*b.w;
    #pragma unroll
    for (int off = 32; off; off >>= 1) s += __shfl_xor(s, off, 64);
    if (lane == 0) *sq = s;
}

// ---- pass 2: fused GEMM + RBF epilogue ----
__global__ __launch_bounds__(256, 2) void rbf_gemm(
    const __bf16* __restrict__ Xbf,  // [8192][512]
    const __bf16* __restrict__ Cbf,  // [1024][512]
    const float* __restrict__ LS,    // [1024]
    const float* __restrict__ xsq,   // [8192]
    const float* __restrict__ csq,   // [1024]
    float* __restrict__ out)         // [8192][1024]
{
    __shared__ __bf16 As[2][128 * BK];   // 16 KB each buf
    __shared__ __bf16 Bs[2][128 * BK];

    const int tid  = threadIdx.x;
    // XCD-aware swizzle: 512 blocks, 512 % 8 == 0 -> simple form is bijective.
    // XCD x gets bm in [x*8, x*8+8) x all bn: 1MB X-panel + 1MB Cbf per XCD L2.
    const int sid  = blockIdx.x;
    const int bidx = (sid & 7) * 64 + (sid >> 3);
    const int bm   = bidx >> 3;          // 0..63
    const int bn   = bidx & 7;           // 0..7
    const int brow = bm * 128;
    const int bcol = bn * 128;
    const int lane = tid & 63;
    const int w    = tid >> 6;
    const int wr   = w >> 1;             // 2x2 waves, each 64x64 output
    const int wc   = w & 1;
    const int l15  = lane & 15;
    const int l4   = lane >> 4;

    // Staging: per tile 128x64 bf16 = 16KB = 256 thr x 4 x 16B.
    // Load i deposits LDS bytes [tid*16 + i*4096): row = tid/8 + i*32, phys slot = tid&7.
    // Read uses phys slot = kslot ^ (row&7)  =>  source must be inverse-swizzled:
    // this thread fetches global k-slot (tid&7) ^ (row&7). Permutation stays inside
    // one 128B segment -> still line-coalesced.
    const int srow = tid >> 3;                          // 0..31
    const int col8 = (((tid & 7) ^ (srow & 7)) * 8);    // inverse-swizzled k offset
    const __bf16* Asrc = Xbf + (size_t)(brow + srow) * IN_K + col8;
    const __bf16* Bsrc = Cbf + (size_t)(bcol + srow) * IN_K + col8;

    auto stage = [&](int kt, int buf) {
        #pragma unroll
        for (int i = 0; i < 4; ++i)
            gload_lds16(Asrc + (size_t)i * 32 * IN_K + kt * BK, &As[buf][tid * 8 + i * 2048]);
        #pragma unroll
        for (int i = 0; i < 4; ++i)
            gload_lds16(Bsrc + (size_t)i * 32 * IN_K + kt * BK, &Bs[buf][tid * 8 + i * 2048]);
    };

    floatx4 acc[4][4];
    #pragma unroll
    for (int m = 0; m < 4; ++m)
        #pragma unroll
        for (int n = 0; n < 4; ++n)
            acc[m][n] = (floatx4){0.f, 0.f, 0.f, 0.f};

    stage(0, 0);

    #pragma unroll 1
    for (int kt = 0; kt < NKT; ++kt) {
        const int cur = kt & 1;
        __syncthreads();                        // drains vmcnt: buf[cur] ready
        if (kt < NKT - 1) stage(kt + 1, cur ^ 1);  // overlap next loads with MFMA below

        #pragma unroll
        for (int ks = 0; ks < 2; ++ks) {        // two k=32 sub-steps of the BK=64 tile
            bf16x8 af[4], bfr[4];
            #pragma unroll
            for (int m = 0; m < 4; ++m) {
                int r = wr * 64 + m * 16 + l15;
                int kslot = l4 + ks * 4;
                af[m] = *reinterpret_cast<const bf16x8*>(
                    &As[cur][r * BK + ((kslot ^ (r & 7)) * 8)]);
            }
            #pragma unroll
            for (int n = 0; n < 4; ++n) {
                int r = wc * 64 + n * 16 + l15;
                int kslot = l4 + ks * 4;
                bfr[n] = *reinterpret_cast<const bf16x8*>(
                    &Bs[cur][r * BK + ((kslot ^ (r & 7)) * 8)]);
            }
            #pragma unroll
            for (int m = 0; m < 4; ++m)
                #pragma unroll
                for (int n = 0; n < 4; ++n)
                    acc[m][n] = __builtin_amdgcn_mfma_f32_16x16x32_bf16(af[m], bfr[n], acc[m][n], 0, 0, 0);
        }
    }

    // Epilogue: d2 = max(xsq + csq - 2*cross, 0); out = exp(-d2 * exp(-2*ls))
    float xs[4][4];
    #pragma unroll
    for (int m = 0; m < 4; ++m) {
        int row0 = brow + wr * 64 + m * 16 + l4 * 4;
        #pragma unroll
        for (int r = 0; r < 4; ++r) xs[m][r] = xsq[row0 + r];
    }

    #pragma unroll
    for (int n = 0; n < 4; ++n) {
        int col   = bcol + wc * 64 + n * 16 + l15;
        float cs  = csq[col];
        float inv = __expf(-2.f * LS[col]);
        #pragma unroll
        for (int m = 0; m < 4; ++m) {
            int row0 = brow + wr * 64 + m * 16 + l4 * 4;
            #pragma unroll
            for (int r = 0; r < 4; ++r) {
                float cross = acc[m][n][r];
                float d2 = fmaxf(xs[m][r] + cs - 2.f * cross, 0.f);
                out[(size_t)(row0 + r) * OUT_N + col] = __expf(-d2 * inv);
            }
        }
    }
}

extern "C" void kernel_launch(void* const* d_in, const int* in_sizes, int n_in,
                              void* d_out, int out_size, void* d_ws, size_t ws_size,
                              hipStream_t stream) {
    const float* X  = (const float*)d_in[0];   // input   [8192][512]
    const float* C  = (const float*)d_in[1];   // centres [1024][512]
    const float* LS = (const float*)d_in[2];   // log_sigmas [1024]
    float* out = (float*)d_out;

    // workspace layout
    float*  xsq = (float*)d_ws;                                   // 8192 f32
    float*  csq = (float*)((char*)d_ws + 32768);                  // 1024 f32
    __bf16* Xbf = (__bf16*)((char*)d_ws + 65536);                 // 8.4 MB
    __bf16* Cbf = (__bf16*)((char*)d_ws + 65536 + (size_t)B_ROWS * IN_K * 2); // 1 MB

    convert_sumsq<<<(B_ROWS + OUT_N) / 4, 256, 0, stream>>>(X, C, Xbf, Cbf, xsq, csq);
    rbf_gemm<<<(B_ROWS / 128) * (OUT_N / 128), 256, 0, stream>>>(Xbf, Cbf, LS, xsq, csq, out);
}